// Round 9
// baseline (274.711 us; speedup 1.0000x reference)
//
#include <hip/hip_runtime.h>
#include <hip/hip_fp16.h>

#define H   128
#define ND  64
#define TILE_R 64
#define CAP 64            // edge slots per node; Poisson(16) max over 50K ~ 42
#define POOLB 256         // pool partial blocks

typedef _Float16 f16x8 __attribute__((ext_vector_type(8)));
typedef float    f32x4 __attribute__((ext_vector_type(4)));

__device__ __forceinline__ unsigned short f2h(float f) {
  return __half_as_ushort(__float2half(f));
}
__device__ __forceinline__ float h2f(unsigned short u) {
  return __half2float(__ushort_as_half(u));
}

// swizzled msg-tile offset (ushort index): row*256B, 16B-col XOR (row&15).
// MFMA-read lanes vary row with fixed col -> (col^row) spreads across all 16
// 16B slots of the row -> ~conflict-free (verified R4/R5: SQ_LDS_BANK_CONFLICT~0).
__device__ __forceinline__ int smoff(int row, int col16) {
  return row * H + (((col16) ^ (row & 15)) << 3);
}

// ---------------- prep: weight frags + zero cnt -----------------------------

__global__ __launch_bounds__(256) void prep_all_k(const float* __restrict__ Wg,
                                                  const float* __restrict__ Wp,
                                                  unsigned short* __restrict__ wfrag,
                                                  unsigned short* __restrict__ wpfrag,
                                                  int* __restrict__ cnt, int n_pad) {
  __shared__ float sW[H * H];
  if (blockIdx.x < 3) {
    const float* W = Wg + (size_t)blockIdx.x * H * H;
    for (int i = threadIdx.x; i < H * H; i += 256) sW[i] = W[i];
    __syncthreads();
    unsigned short* out = wfrag + (size_t)blockIdx.x * 2048 * 8;
    for (int c = threadIdx.x; c < 2048; c += 256) {
      int lane = c & 63, combo = c >> 6;
      int it = combo >> 2, ks = combo & 3;
      int nc = it * 16 + (lane & 15);
      int kb = ks * 32 + (lane >> 4) * 8;
      unsigned short* o = out + (size_t)c * 8;
#pragma unroll
      for (int j = 0; j < 8; ++j) o[j] = f2h(sW[(kb + j) * H + nc]);
    }
  } else if (blockIdx.x == 3) {
    for (int i = threadIdx.x; i < ND * H; i += 256) sW[i] = Wp[i];
    __syncthreads();
    for (int c = threadIdx.x; c < 1024; c += 256) {
      int lane = c & 63, combo = c >> 6;
      int it = combo >> 1, ks = combo & 1;
      int nc = it * 16 + (lane & 15);
      int kb = ks * 32 + (lane >> 4) * 8;
      unsigned short* o = wpfrag + (size_t)c * 8;
#pragma unroll
      for (int j = 0; j < 8; ++j) o[j] = f2h(sW[(kb + j) * H + nc]);
    }
  } else {
    int zb = blockIdx.x - 4;                      // 0..15
    int chunk = (n_pad + 15) >> 4;
    int lo = zb * chunk, hi = lo + chunk; if (hi > n_pad) hi = n_pad;
    for (int i = lo + threadIdx.x; i < hi; i += 256) cnt[i] = 0;
  }
}

// ---------------- merged: one-pass scatter || node projection ---------------
// R9: each edge handled by exactly ONE thread (no XCD partition, no 8x scan).
// 800K atomics over 3128 cachelines (far below the pool_mlp contention
// regime); ssrc stores are disjoint-byte, merged by byte-enables at
// eviction. Scan traffic drops 51.2 MB -> 6.4 MB, no per-thread loop.

__global__ __launch_bounds__(256) void scatter_proj_k(
    const int* __restrict__ src, const int* __restrict__ dst,
    int* __restrict__ cnt, unsigned short* __restrict__ ssrc, int E, int scb,
    const float* __restrict__ x, const unsigned short* __restrict__ wpfrag,
    const float* __restrict__ bp, unsigned short* __restrict__ hout, int n) {
  __shared__ unsigned short sB[1024 * 8];         // 16 KB (proj B-frags)
  if ((int)blockIdx.x < scb) {
    int e = (int)blockIdx.x * 256 + (int)threadIdx.x;
    if (e < E) {
      int d = dst[e];
      int p = atomicAdd(&cnt[d], 1);
      if (p < CAP) ssrc[(size_t)d * CAP + p] = (unsigned short)src[e];
    }
    return;
  }

  uint4* sB4 = (uint4*)sB;
  const uint4* wsrc = (const uint4*)wpfrag;
  for (int i = threadIdx.x; i < 1024; i += 256) sB4[i] = wsrc[i];
  __syncthreads();

  int wave = threadIdx.x >> 6, lane = threadIdx.x & 63;
  int quad = lane >> 4, n16 = lane & 15;
  int node = ((int)blockIdx.x - scb) * 64 + wave * 16 + n16;

  union { unsigned short s[8]; uint4 u; f16x8 h; } bm[2];
  if (node < n) {
    const float* xr = x + (size_t)node * ND;
#pragma unroll
    for (int ks = 0; ks < 2; ++ks) {
      const float* pk = xr + ks * 32 + quad * 8;
      float4 A0 = *(const float4*)pk;
      float4 A1 = *(const float4*)(pk + 4);
      bm[ks].s[0] = f2h(A0.x); bm[ks].s[1] = f2h(A0.y);
      bm[ks].s[2] = f2h(A0.z); bm[ks].s[3] = f2h(A0.w);
      bm[ks].s[4] = f2h(A1.x); bm[ks].s[5] = f2h(A1.y);
      bm[ks].s[6] = f2h(A1.z); bm[ks].s[7] = f2h(A1.w);
    }
  } else {
    bm[0].u = make_uint4(0, 0, 0, 0);
    bm[1].u = make_uint4(0, 0, 0, 0);
  }

  f32x4 acc[8] = {};
#pragma unroll
  for (int it = 0; it < 8; ++it) {
#pragma unroll
    for (int ks = 0; ks < 2; ++ks) {
      union { uint4 u; f16x8 h; } aw;
      aw.u = sB4[(it * 2 + ks) * 64 + lane];
      acc[it] = __builtin_amdgcn_mfma_f32_16x16x32_f16(aw.h, bm[ks].h, acc[it], 0, 0, 0);
    }
  }

  unsigned short* rout = hout + (size_t)node * H;
#pragma unroll
  for (int it = 0; it < 8; ++it) {
    int f0 = it * 16 + quad * 4;
    float4 bv = *(const float4*)(bp + f0);
    ushort4 o = make_ushort4(f2h(acc[it][0] + bv.x), f2h(acc[it][1] + bv.y),
                             f2h(acc[it][2] + bv.z), f2h(acc[it][3] + bv.w));
    *(ushort4*)(rout + f0) = o;
  }
}

// ---------------- fused layer v2: 32 nodes/block, 4 gather chains/wave ------

__global__ __launch_bounds__(512) void layer_fused512_k(
    const unsigned short* __restrict__ hin,
    unsigned short* __restrict__ hout,
    const int* __restrict__ cnt,
    const unsigned short* __restrict__ ssrc,
    const unsigned short* __restrict__ wfrag,
    const float* __restrict__ bg) {
  __shared__ unsigned short sW[2048 * 8];   // 32 KB weight frags
  __shared__ unsigned short sM[32 * H];     // 8 KB msg tile (swizzled)
  uint4* sW4 = (uint4*)sW;
  const uint4* wsrc = (const uint4*)wfrag;
  for (int i = threadIdx.x; i < 2048; i += 512) sW4[i] = wsrc[i];

  int wave = threadIdx.x >> 6, lane = threadIdx.x & 63;
  int sub = lane >> 4, li = lane & 15;
  int nbase = (int)blockIdx.x * 32;

  int deg[4], eid[4];
#pragma unroll
  for (int c = 0; c < 4; ++c) {
    int nd = nbase + wave * 4 + c;
    int dg = cnt[nd]; if (dg > CAP) dg = CAP;
    deg[c] = dg;
    eid[c] = (int)ssrc[(size_t)nd * CAP + (lane < dg ? lane : 0)];
  }
  const __half2 z = __floats2half2_rn(0.f, 0.f);
  __half2 ac[4][4];
#pragma unroll
  for (int c = 0; c < 4; ++c)
#pragma unroll
    for (int k = 0; k < 4; ++k) ac[c][k] = z;

  int mx = deg[0];
#pragma unroll
  for (int c = 1; c < 4; ++c) if (deg[c] > mx) mx = deg[c];

#pragma unroll 2
  for (int j = 0; j < mx; j += 4) {            // wave-uniform trip count
    int jj = j + sub;
#pragma unroll
    for (int c = 0; c < 4; ++c) {
      int s = __shfl(eid[c], jj < deg[c] ? jj : 0, 64);
      if (jj < deg[c]) {
        union { uint4 u; __half2 h[4]; } v;
        v.u = *(const uint4*)(hin + (size_t)s * H + li * 8);
        ac[c][0] = __hadd2(ac[c][0], v.h[0]);
        ac[c][1] = __hadd2(ac[c][1], v.h[1]);
        ac[c][2] = __hadd2(ac[c][2], v.h[2]);
        ac[c][3] = __hadd2(ac[c][3], v.h[3]);
      }
    }
  }

#pragma unroll
  for (int c = 0; c < 4; ++c) {
    int row = wave * 4 + c;
#pragma unroll
    for (int k = 0; k < 4; ++k) {
      union { __half2 h; unsigned int u; } a, b, d;
      a.h = ac[c][k];
      b.u = __shfl_xor(a.u, 16, 64);
      a.h = __hadd2(a.h, b.h);
      d.u = __shfl_xor(a.u, 32, 64);
      ac[c][k] = __hadd2(a.h, d.h);
    }
    if (sub == 0) {
      float inv = (deg[c] > 0) ? 1.0f / (float)deg[c] : 0.f;
      uint4 o;
      unsigned int* op = (unsigned int*)&o;
#pragma unroll
      for (int k = 0; k < 4; ++k) {
        float lo = __low2float(ac[c][k]) * inv;
        float hi = __high2float(ac[c][k]) * inv;
        op[k] = (unsigned int)f2h(lo) | ((unsigned int)f2h(hi) << 16);
      }
      *(uint4*)&sM[smoff(row, li)] = o;
    }
  }
  __syncthreads();

  // ---- MFMA: wave w -> out-cols [w*16, w*16+16) of the block's 32 nodes ----
  int quad = sub, n16 = li;
  int f0 = wave * 16 + quad * 4;
  float4 bv = *(const float4*)(bg + f0);
#pragma unroll
  for (int t = 0; t < 2; ++t) {
    union { uint4 u; f16x8 h; } bm[4];
#pragma unroll
    for (int ks = 0; ks < 4; ++ks)
      bm[ks].u = *(const uint4*)&sM[smoff(t * 16 + n16, ks * 4 + quad)];

    f32x4 acc = {};
#pragma unroll
    for (int ks = 0; ks < 4; ++ks) {
      union { uint4 u; f16x8 h; } aw;
      aw.u = sW4[(wave * 4 + ks) * 64 + lane];
      acc = __builtin_amdgcn_mfma_f32_16x16x32_f16(aw.h, bm[ks].h, acc, 0, 0, 0);
    }

    int node = nbase + t * 16 + n16;
    ushort4 old = *(const ushort4*)(hin + (size_t)node * H + f0);
    float v0 = h2f(old.x) + acc[0] + bv.x; v0 = v0 > 0.f ? v0 : 0.f;
    float v1 = h2f(old.y) + acc[1] + bv.y; v1 = v1 > 0.f ? v1 : 0.f;
    float v2 = h2f(old.z) + acc[2] + bv.z; v2 = v2 > 0.f ? v2 : 0.f;
    float v3 = h2f(old.w) + acc[3] + bv.w; v3 = v3 > 0.f ? v3 : 0.f;
    *(ushort4*)(hout + (size_t)node * H + f0) = make_ushort4(f2h(v0), f2h(v1),
                                                             f2h(v2), f2h(v3));
  }
}

// ---------------- pool stage 1: per-block partial sums (NO atomics) ---------

__global__ __launch_bounds__(256) void pool_part_k(
    const unsigned short* __restrict__ hb, float* __restrict__ partial, int n) {
  int c  = threadIdx.x & 31;
  int rg = threadIdx.x >> 5;
  float4 acc = {0.f, 0.f, 0.f, 0.f};
#pragma unroll 4
  for (int row = blockIdx.x * 8 + rg; row < n; row += gridDim.x * 8) {
    ushort4 v = ((const ushort4*)(hb + (size_t)row * H))[c];
    acc.x += h2f(v.x); acc.y += h2f(v.y);
    acc.z += h2f(v.z); acc.w += h2f(v.w);
  }
  __shared__ float4 s[256];
  s[threadIdx.x] = acc;
  __syncthreads();
  if (threadIdx.x < 32) {
    float4 t = s[c];
#pragma unroll
    for (int k = 1; k < 8; ++k) {
      float4 q = s[k * 32 + c];
      t.x += q.x; t.y += q.y; t.z += q.z; t.w += q.w;
    }
    *(float4*)&partial[(size_t)blockIdx.x * H + c * 4] = t;
  }
}

// ---------------- pool stage 2: reduce partials + MLP head (1 block) --------

__global__ __launch_bounds__(256) void mlp_k(
    const float* __restrict__ partial,
    const float* __restrict__ W1, const float* __restrict__ b1,
    const float* __restrict__ W2, const float* __restrict__ b2,
    float* __restrict__ out, float invN) {
  __shared__ float g[H];
  __shared__ float hid[H];
  __shared__ float hpart[256];
  __shared__ float gpart[256];
  int tid = threadIdx.x;

  // reduce 256 partial vectors: thread t sums element (t&127) over half the blocks
  {
    int e = tid & 127, half = tid >> 7;
    const float* pp = partial + (size_t)(half * (POOLB / 2)) * H + e;
    float p0 = 0.f, p1 = 0.f, p2 = 0.f, p3 = 0.f;
#pragma unroll 4
    for (int b = 0; b < POOLB / 2; b += 4) {
      p0 += pp[(size_t)(b + 0) * H];
      p1 += pp[(size_t)(b + 1) * H];
      p2 += pp[(size_t)(b + 2) * H];
      p3 += pp[(size_t)(b + 3) * H];
    }
    gpart[tid] = (p0 + p1) + (p2 + p3);
  }
  __syncthreads();
  if (tid < H) g[tid] = (gpart[tid] + gpart[tid + 128]) * invN;
  __syncthreads();

  {
    int o = tid & 127, half = tid >> 7;
    int k0 = half * 64;
    float p0 = 0.f, p1 = 0.f, p2 = 0.f, p3 = 0.f;
#pragma unroll
    for (int k = 0; k < 64; k += 4) {
      p0 += g[k0 + k + 0] * W1[(k0 + k + 0) * H + o];
      p1 += g[k0 + k + 1] * W1[(k0 + k + 1) * H + o];
      p2 += g[k0 + k + 2] * W1[(k0 + k + 2) * H + o];
      p3 += g[k0 + k + 3] * W1[(k0 + k + 3) * H + o];
    }
    hpart[tid] = (p0 + p1) + (p2 + p3);
  }
  __syncthreads();
  if (tid < H) {
    float v = hpart[tid] + hpart[tid + 128] + b1[tid];
    hid[tid] = v > 0.f ? v : 0.f;
  }
  __syncthreads();
  {
    float q0 = 0.f, q1 = 0.f, q2 = 0.f, q3 = 0.f;
#pragma unroll
    for (int k = 0; k < H; k += 4) {
      q0 += hid[k + 0] * W2[(k + 0) * 256 + tid];
      q1 += hid[k + 1] * W2[(k + 1) * 256 + tid];
      q2 += hid[k + 2] * W2[(k + 2) * 256 + tid];
      q3 += hid[k + 3] * W2[(k + 3) * 256 + tid];
    }
    out[tid] = b2[tid] + (q0 + q1) + (q2 + q3);
  }
}

// ---------------- launcher ----------------

extern "C" void kernel_launch(void* const* d_in, const int* in_sizes, int n_in,
                              void* d_out, int out_size, void* d_ws, size_t ws_size,
                              hipStream_t stream) {
  const float* x  = (const float*)d_in[0];
  const int*   src = (const int*)d_in[1];
  const int*   dst = (const int*)d_in[2];
  const float* Wp = (const float*)d_in[3];
  const float* bp = (const float*)d_in[4];
  const float* Wg = (const float*)d_in[5];
  const float* bg = (const float*)d_in[6];
  const float* W1 = (const float*)d_in[7];
  const float* b1 = (const float*)d_in[8];
  const float* W2 = (const float*)d_in[9];
  const float* b2 = (const float*)d_in[10];
  float* out = (float*)d_out;

  const int N = in_sizes[0] / ND;   // 50000 (< 65536 — ssrc is ushort)
  const int E = in_sizes[1];        // 800000
  const int N_pad = ((N + TILE_R - 1) / TILE_R) * TILE_R;   // 50048 (div by 64)
  const size_t NH = (size_t)N_pad * H;
  const int scb = (E + 255) / 256;                          // 3125 scatter blocks

  char* p = (char*)d_ws;
  unsigned short* hb0   = (unsigned short*)p; p += NH * sizeof(unsigned short);
  unsigned short* hb1   = (unsigned short*)p; p += NH * sizeof(unsigned short);
  unsigned short* msgh  = (unsigned short*)p; p += NH * sizeof(unsigned short);  // unused (layout keep)
  unsigned short* wfrag = (unsigned short*)p; p += 3 * 2048 * 8 * sizeof(unsigned short);
  unsigned short* wpfrag= (unsigned short*)p; p += 1024 * 8 * sizeof(unsigned short);
  unsigned short* ssrc  = (unsigned short*)p; p += (size_t)N_pad * CAP * sizeof(unsigned short);
  int*   cnt  = (int*)p;   p += (size_t)N_pad * sizeof(int);
  float* partial = (float*)p; p += (size_t)POOLB * H * sizeof(float);
  (void)msgh;

  const int ntiles = N_pad / TILE_R;

  // D1: weight prep + zero cnt
  prep_all_k<<<20, 256, 0, stream>>>(Wg, Wp, wfrag, wpfrag, cnt, N_pad);

  // D2: one-pass scatter || proj (independent; overlapped in one dispatch)
  scatter_proj_k<<<scb + ntiles, 256, 0, stream>>>(src, dst, cnt, ssrc, E, scb,
                                                   x, wpfrag, bp, hb0, N);

  // D3-D5: 3 fused GNN layers (32 nodes/block, 4 chains/wave)
  unsigned short* hin = hb0;
  unsigned short* hout = hb1;
  for (int l = 0; l < 3; ++l) {
    layer_fused512_k<<<N_pad / 32, 512, 0, stream>>>(hin, hout, cnt, ssrc,
                                                     wfrag + (size_t)l * 2048 * 8,
                                                     bg + (size_t)l * H);
    unsigned short* t = hin; hin = hout; hout = t;
  }

  // D6: pool partials (no atomics)   D7: reduce + MLP head
  pool_part_k<<<POOLB, 256, 0, stream>>>(hin, partial, N);
  mlp_k<<<1, 256, 0, stream>>>(partial, W1, b1, W2, b2, out, 1.0f / (float)N);
}

// Round 10
// 254.086 us; speedup vs baseline: 1.0812x; 1.0812x over previous
//
#include <hip/hip_runtime.h>
#include <hip/hip_fp16.h>

#define H   128
#define ND  64
#define TILE_R 64
#define CAP 64            // edge slots per node; Poisson(16) max over 50K ~ 42
#define NSCAT 2048        // scatter blocks (XCD-partitioned, &7)
#define POOLB 256         // pool partial blocks

typedef _Float16 f16x8 __attribute__((ext_vector_type(8)));
typedef float    f32x4 __attribute__((ext_vector_type(4)));
typedef int      i32x4 __attribute__((ext_vector_type(4)));

__device__ __forceinline__ unsigned short f2h(float f) {
  return __half_as_ushort(__float2half(f));
}
__device__ __forceinline__ float h2f(unsigned short u) {
  return __half2float(__ushort_as_half(u));
}

// swizzled msg-tile offset (ushort index): row*256B, 16B-col XOR (row&15).
// MFMA-read lanes vary row with fixed col -> (col^row) spreads across all 16
// 16B slots of the row -> ~conflict-free (verified R4/R5: SQ_LDS_BANK_CONFLICT~0).
__device__ __forceinline__ int smoff(int row, int col16) {
  return row * H + (((col16) ^ (row & 15)) << 3);
}

// ---------------- prep: weight frags + zero cnt -----------------------------

__global__ __launch_bounds__(256) void prep_all_k(const float* __restrict__ Wg,
                                                  const float* __restrict__ Wp,
                                                  unsigned short* __restrict__ wfrag,
                                                  unsigned short* __restrict__ wpfrag,
                                                  int* __restrict__ cnt, int n_pad) {
  __shared__ float sW[H * H];
  if (blockIdx.x < 3) {
    const float* W = Wg + (size_t)blockIdx.x * H * H;
    for (int i = threadIdx.x; i < H * H; i += 256) sW[i] = W[i];
    __syncthreads();
    unsigned short* out = wfrag + (size_t)blockIdx.x * 2048 * 8;
    for (int c = threadIdx.x; c < 2048; c += 256) {
      int lane = c & 63, combo = c >> 6;
      int it = combo >> 2, ks = combo & 3;
      int nc = it * 16 + (lane & 15);
      int kb = ks * 32 + (lane >> 4) * 8;
      unsigned short* o = out + (size_t)c * 8;
#pragma unroll
      for (int j = 0; j < 8; ++j) o[j] = f2h(sW[(kb + j) * H + nc]);
    }
  } else if (blockIdx.x == 3) {
    for (int i = threadIdx.x; i < ND * H; i += 256) sW[i] = Wp[i];
    __syncthreads();
    for (int c = threadIdx.x; c < 1024; c += 256) {
      int lane = c & 63, combo = c >> 6;
      int it = combo >> 1, ks = combo & 1;
      int nc = it * 16 + (lane & 15);
      int kb = ks * 32 + (lane >> 4) * 8;
      unsigned short* o = wpfrag + (size_t)c * 8;
#pragma unroll
      for (int j = 0; j < 8; ++j) o[j] = f2h(sW[(kb + j) * H + nc]);
    }
  } else {
    int zb = blockIdx.x - 4;                      // 0..15
    int chunk = (n_pad + 15) >> 4;
    int lo = zb * chunk, hi = lo + chunk; if (hi > n_pad) hi = n_pad;
    for (int i = lo + threadIdx.x; i < hi; i += 256) cnt[i] = 0;
  }
}

// ---------------- merged: XCD-partitioned scatter || node projection --------
// R10: 8-group XCD partition retained (R9 proved atomic homing is worth more
// than the 8x scan: one-pass was 70us, WRITE 43->57MB from cross-XCD line
// ping-pong). Scan cost cut via int4 dst loads in the loop-carried form:
// ~3 iterations/thread instead of 12, per-iteration atomic throttle kept.
// (int4+nt was 53us — nt's L3 bypass cost; int4 cached is the untested cell.)

__global__ __launch_bounds__(256) void scatter_proj_k(
    const int* __restrict__ src, const int* __restrict__ dst,
    int* __restrict__ cnt, unsigned short* __restrict__ ssrc, int E, int psz,
    const float* __restrict__ x, const unsigned short* __restrict__ wpfrag,
    const float* __restrict__ bp, unsigned short* __restrict__ hout, int n) {
  __shared__ unsigned short sB[1024 * 8];         // 16 KB (proj B-frags)
  if ((int)blockIdx.x < NSCAT) {
    int grp = blockIdx.x & 7;
    int lo = grp * psz, hi = lo + psz;
    int base = ((int)blockIdx.x >> 3) * 1024 + (int)threadIdx.x * 4;
    const int stride = (NSCAT >> 3) * 1024;       // 262144; E%4==0, base%4==0
    for (int e = base; e < E; e += stride) {
      i32x4 d4 = *(const i32x4*)(dst + e);
#pragma unroll
      for (int j = 0; j < 4; ++j) {
        int d = d4[j];
        if (d >= lo && d < hi) {
          int p = atomicAdd(&cnt[d], 1);
          if (p < CAP) ssrc[(size_t)d * CAP + p] = (unsigned short)src[e + j];
        }
      }
    }
    return;
  }

  uint4* sB4 = (uint4*)sB;
  const uint4* wsrc = (const uint4*)wpfrag;
  for (int i = threadIdx.x; i < 1024; i += 256) sB4[i] = wsrc[i];
  __syncthreads();

  int wave = threadIdx.x >> 6, lane = threadIdx.x & 63;
  int quad = lane >> 4, n16 = lane & 15;
  int node = ((int)blockIdx.x - NSCAT) * 64 + wave * 16 + n16;

  union { unsigned short s[8]; uint4 u; f16x8 h; } bm[2];
  if (node < n) {
    const float* xr = x + (size_t)node * ND;
#pragma unroll
    for (int ks = 0; ks < 2; ++ks) {
      const float* pk = xr + ks * 32 + quad * 8;
      float4 A0 = *(const float4*)pk;
      float4 A1 = *(const float4*)(pk + 4);
      bm[ks].s[0] = f2h(A0.x); bm[ks].s[1] = f2h(A0.y);
      bm[ks].s[2] = f2h(A0.z); bm[ks].s[3] = f2h(A0.w);
      bm[ks].s[4] = f2h(A1.x); bm[ks].s[5] = f2h(A1.y);
      bm[ks].s[6] = f2h(A1.z); bm[ks].s[7] = f2h(A1.w);
    }
  } else {
    bm[0].u = make_uint4(0, 0, 0, 0);
    bm[1].u = make_uint4(0, 0, 0, 0);
  }

  f32x4 acc[8] = {};
#pragma unroll
  for (int it = 0; it < 8; ++it) {
#pragma unroll
    for (int ks = 0; ks < 2; ++ks) {
      union { uint4 u; f16x8 h; } aw;
      aw.u = sB4[(it * 2 + ks) * 64 + lane];
      acc[it] = __builtin_amdgcn_mfma_f32_16x16x32_f16(aw.h, bm[ks].h, acc[it], 0, 0, 0);
    }
  }

  unsigned short* rout = hout + (size_t)node * H;
#pragma unroll
  for (int it = 0; it < 8; ++it) {
    int f0 = it * 16 + quad * 4;
    float4 bv = *(const float4*)(bp + f0);
    ushort4 o = make_ushort4(f2h(acc[it][0] + bv.x), f2h(acc[it][1] + bv.y),
                             f2h(acc[it][2] + bv.z), f2h(acc[it][3] + bv.w));
    *(ushort4*)(rout + f0) = o;
  }
}

// ---------------- fused layer v2: 32 nodes/block, 4 gather chains/wave ------

__global__ __launch_bounds__(512) void layer_fused512_k(
    const unsigned short* __restrict__ hin,
    unsigned short* __restrict__ hout,
    const int* __restrict__ cnt,
    const unsigned short* __restrict__ ssrc,
    const unsigned short* __restrict__ wfrag,
    const float* __restrict__ bg) {
  __shared__ unsigned short sW[2048 * 8];   // 32 KB weight frags
  __shared__ unsigned short sM[32 * H];     // 8 KB msg tile (swizzled)
  uint4* sW4 = (uint4*)sW;
  const uint4* wsrc = (const uint4*)wfrag;
  for (int i = threadIdx.x; i < 2048; i += 512) sW4[i] = wsrc[i];

  int wave = threadIdx.x >> 6, lane = threadIdx.x & 63;
  int sub = lane >> 4, li = lane & 15;
  int nbase = (int)blockIdx.x * 32;

  int deg[4], eid[4];
#pragma unroll
  for (int c = 0; c < 4; ++c) {
    int nd = nbase + wave * 4 + c;
    int dg = cnt[nd]; if (dg > CAP) dg = CAP;
    deg[c] = dg;
    eid[c] = (int)ssrc[(size_t)nd * CAP + (lane < dg ? lane : 0)];
  }
  const __half2 z = __floats2half2_rn(0.f, 0.f);
  __half2 ac[4][4];
#pragma unroll
  for (int c = 0; c < 4; ++c)
#pragma unroll
    for (int k = 0; k < 4; ++k) ac[c][k] = z;

  int mx = deg[0];
#pragma unroll
  for (int c = 1; c < 4; ++c) if (deg[c] > mx) mx = deg[c];

#pragma unroll 2
  for (int j = 0; j < mx; j += 4) {            // wave-uniform trip count
    int jj = j + sub;
#pragma unroll
    for (int c = 0; c < 4; ++c) {
      int s = __shfl(eid[c], jj < deg[c] ? jj : 0, 64);
      if (jj < deg[c]) {
        union { uint4 u; __half2 h[4]; } v;
        v.u = *(const uint4*)(hin + (size_t)s * H + li * 8);
        ac[c][0] = __hadd2(ac[c][0], v.h[0]);
        ac[c][1] = __hadd2(ac[c][1], v.h[1]);
        ac[c][2] = __hadd2(ac[c][2], v.h[2]);
        ac[c][3] = __hadd2(ac[c][3], v.h[3]);
      }
    }
  }

#pragma unroll
  for (int c = 0; c < 4; ++c) {
    int row = wave * 4 + c;
#pragma unroll
    for (int k = 0; k < 4; ++k) {
      union { __half2 h; unsigned int u; } a, b, d;
      a.h = ac[c][k];
      b.u = __shfl_xor(a.u, 16, 64);
      a.h = __hadd2(a.h, b.h);
      d.u = __shfl_xor(a.u, 32, 64);
      ac[c][k] = __hadd2(a.h, d.h);
    }
    if (sub == 0) {
      float inv = (deg[c] > 0) ? 1.0f / (float)deg[c] : 0.f;
      uint4 o;
      unsigned int* op = (unsigned int*)&o;
#pragma unroll
      for (int k = 0; k < 4; ++k) {
        float lo = __low2float(ac[c][k]) * inv;
        float hi = __high2float(ac[c][k]) * inv;
        op[k] = (unsigned int)f2h(lo) | ((unsigned int)f2h(hi) << 16);
      }
      *(uint4*)&sM[smoff(row, li)] = o;
    }
  }
  __syncthreads();

  // ---- MFMA: wave w -> out-cols [w*16, w*16+16) of the block's 32 nodes ----
  int quad = sub, n16 = li;
  int f0 = wave * 16 + quad * 4;
  float4 bv = *(const float4*)(bg + f0);
#pragma unroll
  for (int t = 0; t < 2; ++t) {
    union { uint4 u; f16x8 h; } bm[4];
#pragma unroll
    for (int ks = 0; ks < 4; ++ks)
      bm[ks].u = *(const uint4*)&sM[smoff(t * 16 + n16, ks * 4 + quad)];

    f32x4 acc = {};
#pragma unroll
    for (int ks = 0; ks < 4; ++ks) {
      union { uint4 u; f16x8 h; } aw;
      aw.u = sW4[(wave * 4 + ks) * 64 + lane];
      acc = __builtin_amdgcn_mfma_f32_16x16x32_f16(aw.h, bm[ks].h, acc, 0, 0, 0);
    }

    int node = nbase + t * 16 + n16;
    ushort4 old = *(const ushort4*)(hin + (size_t)node * H + f0);
    float v0 = h2f(old.x) + acc[0] + bv.x; v0 = v0 > 0.f ? v0 : 0.f;
    float v1 = h2f(old.y) + acc[1] + bv.y; v1 = v1 > 0.f ? v1 : 0.f;
    float v2 = h2f(old.z) + acc[2] + bv.z; v2 = v2 > 0.f ? v2 : 0.f;
    float v3 = h2f(old.w) + acc[3] + bv.w; v3 = v3 > 0.f ? v3 : 0.f;
    *(ushort4*)(hout + (size_t)node * H + f0) = make_ushort4(f2h(v0), f2h(v1),
                                                             f2h(v2), f2h(v3));
  }
}

// ---------------- pool stage 1: per-block partial sums (NO atomics) ---------

__global__ __launch_bounds__(256) void pool_part_k(
    const unsigned short* __restrict__ hb, float* __restrict__ partial, int n) {
  int c  = threadIdx.x & 31;
  int rg = threadIdx.x >> 5;
  float4 acc = {0.f, 0.f, 0.f, 0.f};
#pragma unroll 4
  for (int row = blockIdx.x * 8 + rg; row < n; row += gridDim.x * 8) {
    ushort4 v = ((const ushort4*)(hb + (size_t)row * H))[c];
    acc.x += h2f(v.x); acc.y += h2f(v.y);
    acc.z += h2f(v.z); acc.w += h2f(v.w);
  }
  __shared__ float4 s[256];
  s[threadIdx.x] = acc;
  __syncthreads();
  if (threadIdx.x < 32) {
    float4 t = s[c];
#pragma unroll
    for (int k = 1; k < 8; ++k) {
      float4 q = s[k * 32 + c];
      t.x += q.x; t.y += q.y; t.z += q.z; t.w += q.w;
    }
    *(float4*)&partial[(size_t)blockIdx.x * H + c * 4] = t;
  }
}

// ---------------- pool stage 2: reduce partials + MLP head (1 block) --------

__global__ __launch_bounds__(256) void mlp_k(
    const float* __restrict__ partial,
    const float* __restrict__ W1, const float* __restrict__ b1,
    const float* __restrict__ W2, const float* __restrict__ b2,
    float* __restrict__ out, float invN) {
  __shared__ float g[H];
  __shared__ float hid[H];
  __shared__ float hpart[256];
  __shared__ float gpart[256];
  int tid = threadIdx.x;

  // reduce 256 partial vectors: thread t sums element (t&127) over half the blocks
  {
    int e = tid & 127, half = tid >> 7;
    const float* pp = partial + (size_t)(half * (POOLB / 2)) * H + e;
    float p0 = 0.f, p1 = 0.f, p2 = 0.f, p3 = 0.f;
#pragma unroll 4
    for (int b = 0; b < POOLB / 2; b += 4) {
      p0 += pp[(size_t)(b + 0) * H];
      p1 += pp[(size_t)(b + 1) * H];
      p2 += pp[(size_t)(b + 2) * H];
      p3 += pp[(size_t)(b + 3) * H];
    }
    gpart[tid] = (p0 + p1) + (p2 + p3);
  }
  __syncthreads();
  if (tid < H) g[tid] = (gpart[tid] + gpart[tid + 128]) * invN;
  __syncthreads();

  {
    int o = tid & 127, half = tid >> 7;
    int k0 = half * 64;
    float p0 = 0.f, p1 = 0.f, p2 = 0.f, p3 = 0.f;
#pragma unroll
    for (int k = 0; k < 64; k += 4) {
      p0 += g[k0 + k + 0] * W1[(k0 + k + 0) * H + o];
      p1 += g[k0 + k + 1] * W1[(k0 + k + 1) * H + o];
      p2 += g[k0 + k + 2] * W1[(k0 + k + 2) * H + o];
      p3 += g[k0 + k + 3] * W1[(k0 + k + 3) * H + o];
    }
    hpart[tid] = (p0 + p1) + (p2 + p3);
  }
  __syncthreads();
  if (tid < H) {
    float v = hpart[tid] + hpart[tid + 128] + b1[tid];
    hid[tid] = v > 0.f ? v : 0.f;
  }
  __syncthreads();
  {
    float q0 = 0.f, q1 = 0.f, q2 = 0.f, q3 = 0.f;
#pragma unroll
    for (int k = 0; k < H; k += 4) {
      q0 += hid[k + 0] * W2[(k + 0) * 256 + tid];
      q1 += hid[k + 1] * W2[(k + 1) * 256 + tid];
      q2 += hid[k + 2] * W2[(k + 2) * 256 + tid];
      q3 += hid[k + 3] * W2[(k + 3) * 256 + tid];
    }
    out[tid] = b2[tid] + (q0 + q1) + (q2 + q3);
  }
}

// ---------------- launcher ----------------

extern "C" void kernel_launch(void* const* d_in, const int* in_sizes, int n_in,
                              void* d_out, int out_size, void* d_ws, size_t ws_size,
                              hipStream_t stream) {
  const float* x  = (const float*)d_in[0];
  const int*   src = (const int*)d_in[1];
  const int*   dst = (const int*)d_in[2];
  const float* Wp = (const float*)d_in[3];
  const float* bp = (const float*)d_in[4];
  const float* Wg = (const float*)d_in[5];
  const float* bg = (const float*)d_in[6];
  const float* W1 = (const float*)d_in[7];
  const float* b1 = (const float*)d_in[8];
  const float* W2 = (const float*)d_in[9];
  const float* b2 = (const float*)d_in[10];
  float* out = (float*)d_out;

  const int N = in_sizes[0] / ND;   // 50000 (< 65536 — ssrc is ushort)
  const int E = in_sizes[1];        // 800000
  const int N_pad = ((N + TILE_R - 1) / TILE_R) * TILE_R;   // 50048 (div by 64)
  const size_t NH = (size_t)N_pad * H;
  const int psz = (N_pad + 7) / 8;                          // 6256 nodes/partition

  char* p = (char*)d_ws;
  unsigned short* hb0   = (unsigned short*)p; p += NH * sizeof(unsigned short);
  unsigned short* hb1   = (unsigned short*)p; p += NH * sizeof(unsigned short);
  unsigned short* msgh  = (unsigned short*)p; p += NH * sizeof(unsigned short);  // unused (layout keep)
  unsigned short* wfrag = (unsigned short*)p; p += 3 * 2048 * 8 * sizeof(unsigned short);
  unsigned short* wpfrag= (unsigned short*)p; p += 1024 * 8 * sizeof(unsigned short);
  unsigned short* ssrc  = (unsigned short*)p; p += (size_t)N_pad * CAP * sizeof(unsigned short);
  int*   cnt  = (int*)p;   p += (size_t)N_pad * sizeof(int);
  float* partial = (float*)p; p += (size_t)POOLB * H * sizeof(float);
  (void)msgh;

  const int ntiles = N_pad / TILE_R;

  // D1: weight prep + zero cnt
  prep_all_k<<<20, 256, 0, stream>>>(Wg, Wp, wfrag, wpfrag, cnt, N_pad);

  // D2: scatter || proj (independent; overlapped in one dispatch)
  scatter_proj_k<<<NSCAT + ntiles, 256, 0, stream>>>(src, dst, cnt, ssrc, E, psz,
                                                     x, wpfrag, bp, hb0, N);

  // D3-D5: 3 fused GNN layers (32 nodes/block, 4 chains/wave)
  unsigned short* hin = hb0;
  unsigned short* hout = hb1;
  for (int l = 0; l < 3; ++l) {
    layer_fused512_k<<<N_pad / 32, 512, 0, stream>>>(hin, hout, cnt, ssrc,
                                                     wfrag + (size_t)l * 2048 * 8,
                                                     bg + (size_t)l * H);
    unsigned short* t = hin; hin = hout; hout = t;
  }

  // D6: pool partials (no atomics)   D7: reduce + MLP head
  pool_part_k<<<POOLB, 256, 0, stream>>>(hin, partial, N);
  mlp_k<<<1, 256, 0, stream>>>(partial, W1, b1, W2, b2, out, 1.0f / (float)N);
}

// Round 11
// 250.538 us; speedup vs baseline: 1.0965x; 1.0142x over previous
//
#include <hip/hip_runtime.h>
#include <hip/hip_fp16.h>

#define H   128
#define ND  64
#define TILE_R 64
#define CAP 64            // edge slots per node; Poisson(16) max over 50K ~ 42
#define NSCAT 2048        // scatter blocks (XCD-partitioned, &7)
#define POOLB 256         // pool partial blocks
#define CSTRIDE 16        // cnt padded to one 64B line per node (atomic spread)

typedef _Float16 f16x8 __attribute__((ext_vector_type(8)));
typedef float    f32x4 __attribute__((ext_vector_type(4)));
typedef int      i32x4 __attribute__((ext_vector_type(4)));

__device__ __forceinline__ unsigned short f2h(float f) {
  return __half_as_ushort(__float2half(f));
}
__device__ __forceinline__ float h2f(unsigned short u) {
  return __half2float(__ushort_as_half(u));
}

// swizzled msg-tile offset (ushort index): row*256B, 16B-col XOR (row&15).
__device__ __forceinline__ int smoff(int row, int col16) {
  return row * H + (((col16) ^ (row & 15)) << 3);
}

// ---------------- prep: weight frags + zero cnt -----------------------------

__global__ __launch_bounds__(256) void prep_all_k(const float* __restrict__ Wg,
                                                  const float* __restrict__ Wp,
                                                  unsigned short* __restrict__ wfrag,
                                                  unsigned short* __restrict__ wpfrag,
                                                  int* __restrict__ cnt, int n_pad) {
  __shared__ float sW[H * H];
  if (blockIdx.x < 3) {
    const float* W = Wg + (size_t)blockIdx.x * H * H;
    for (int i = threadIdx.x; i < H * H; i += 256) sW[i] = W[i];
    __syncthreads();
    unsigned short* out = wfrag + (size_t)blockIdx.x * 2048 * 8;
    for (int c = threadIdx.x; c < 2048; c += 256) {
      int lane = c & 63, combo = c >> 6;
      int it = combo >> 2, ks = combo & 3;
      int nc = it * 16 + (lane & 15);
      int kb = ks * 32 + (lane >> 4) * 8;
      unsigned short* o = out + (size_t)c * 8;
#pragma unroll
      for (int j = 0; j < 8; ++j) o[j] = f2h(sW[(kb + j) * H + nc]);
    }
  } else if (blockIdx.x == 3) {
    for (int i = threadIdx.x; i < ND * H; i += 256) sW[i] = Wp[i];
    __syncthreads();
    for (int c = threadIdx.x; c < 1024; c += 256) {
      int lane = c & 63, combo = c >> 6;
      int it = combo >> 1, ks = combo & 1;
      int nc = it * 16 + (lane & 15);
      int kb = ks * 32 + (lane >> 4) * 8;
      unsigned short* o = wpfrag + (size_t)c * 8;
#pragma unroll
      for (int j = 0; j < 8; ++j) o[j] = f2h(sW[(kb + j) * H + nc]);
    }
  } else {
    int zb = blockIdx.x - 4;                      // 0..15
    int chunk = (n_pad + 15) >> 4;
    int lo = zb * chunk, hi = lo + chunk; if (hi > n_pad) hi = n_pad;
    for (int i = lo + threadIdx.x; i < hi; i += 256)
      cnt[(size_t)i * CSTRIDE] = 0;               // only word 0 of each line used
  }
}

// ---------------- merged: XCD-partitioned scatter || node projection --------
// R11: 8-group XCD partition + int4 loop retained. cnt padded to one 64B
// line per node: same-line atomic RMW serialization (~256 ops/line when
// dense) drops 16x. ssrc layout unchanged (plain stores don't RMW).

__global__ __launch_bounds__(256) void scatter_proj_k(
    const int* __restrict__ src, const int* __restrict__ dst,
    int* __restrict__ cnt, unsigned short* __restrict__ ssrc, int E, int psz,
    const float* __restrict__ x, const unsigned short* __restrict__ wpfrag,
    const float* __restrict__ bp, unsigned short* __restrict__ hout, int n) {
  __shared__ unsigned short sB[1024 * 8];         // 16 KB (proj B-frags)
  if ((int)blockIdx.x < NSCAT) {
    int grp = blockIdx.x & 7;
    int lo = grp * psz, hi = lo + psz;
    int base = ((int)blockIdx.x >> 3) * 1024 + (int)threadIdx.x * 4;
    const int stride = (NSCAT >> 3) * 1024;       // 262144; E%4==0, base%4==0
    for (int e = base; e < E; e += stride) {
      i32x4 d4 = *(const i32x4*)(dst + e);
#pragma unroll
      for (int j = 0; j < 4; ++j) {
        int d = d4[j];
        if (d >= lo && d < hi) {
          int p = atomicAdd(&cnt[(size_t)d * CSTRIDE], 1);
          if (p < CAP) ssrc[(size_t)d * CAP + p] = (unsigned short)src[e + j];
        }
      }
    }
    return;
  }

  uint4* sB4 = (uint4*)sB;
  const uint4* wsrc = (const uint4*)wpfrag;
  for (int i = threadIdx.x; i < 1024; i += 256) sB4[i] = wsrc[i];
  __syncthreads();

  int wave = threadIdx.x >> 6, lane = threadIdx.x & 63;
  int quad = lane >> 4, n16 = lane & 15;
  int node = ((int)blockIdx.x - NSCAT) * 64 + wave * 16 + n16;

  union { unsigned short s[8]; uint4 u; f16x8 h; } bm[2];
  if (node < n) {
    const float* xr = x + (size_t)node * ND;
#pragma unroll
    for (int ks = 0; ks < 2; ++ks) {
      const float* pk = xr + ks * 32 + quad * 8;
      float4 A0 = *(const float4*)pk;
      float4 A1 = *(const float4*)(pk + 4);
      bm[ks].s[0] = f2h(A0.x); bm[ks].s[1] = f2h(A0.y);
      bm[ks].s[2] = f2h(A0.z); bm[ks].s[3] = f2h(A0.w);
      bm[ks].s[4] = f2h(A1.x); bm[ks].s[5] = f2h(A1.y);
      bm[ks].s[6] = f2h(A1.z); bm[ks].s[7] = f2h(A1.w);
    }
  } else {
    bm[0].u = make_uint4(0, 0, 0, 0);
    bm[1].u = make_uint4(0, 0, 0, 0);
  }

  f32x4 acc[8] = {};
#pragma unroll
  for (int it = 0; it < 8; ++it) {
#pragma unroll
    for (int ks = 0; ks < 2; ++ks) {
      union { uint4 u; f16x8 h; } aw;
      aw.u = sB4[(it * 2 + ks) * 64 + lane];
      acc[it] = __builtin_amdgcn_mfma_f32_16x16x32_f16(aw.h, bm[ks].h, acc[it], 0, 0, 0);
    }
  }

  unsigned short* rout = hout + (size_t)node * H;
#pragma unroll
  for (int it = 0; it < 8; ++it) {
    int f0 = it * 16 + quad * 4;
    float4 bv = *(const float4*)(bp + f0);
    ushort4 o = make_ushort4(f2h(acc[it][0] + bv.x), f2h(acc[it][1] + bv.y),
                             f2h(acc[it][2] + bv.z), f2h(acc[it][3] + bv.w));
    *(ushort4*)(rout + f0) = o;
  }
}

// ---------------- fused layer v2: 32 nodes/block, 4 gather chains/wave ------

__global__ __launch_bounds__(512) void layer_fused512_k(
    const unsigned short* __restrict__ hin,
    unsigned short* __restrict__ hout,
    const int* __restrict__ cnt,
    const unsigned short* __restrict__ ssrc,
    const unsigned short* __restrict__ wfrag,
    const float* __restrict__ bg) {
  __shared__ unsigned short sW[2048 * 8];   // 32 KB weight frags
  __shared__ unsigned short sM[32 * H];     // 8 KB msg tile (swizzled)
  uint4* sW4 = (uint4*)sW;
  const uint4* wsrc = (const uint4*)wfrag;
  for (int i = threadIdx.x; i < 2048; i += 512) sW4[i] = wsrc[i];

  int wave = threadIdx.x >> 6, lane = threadIdx.x & 63;
  int sub = lane >> 4, li = lane & 15;
  int nbase = (int)blockIdx.x * 32;

  int deg[4], eid[4];
#pragma unroll
  for (int c = 0; c < 4; ++c) {
    int nd = nbase + wave * 4 + c;
    int dg = cnt[(size_t)nd * CSTRIDE]; if (dg > CAP) dg = CAP;
    deg[c] = dg;
    eid[c] = (int)ssrc[(size_t)nd * CAP + (lane < dg ? lane : 0)];
  }
  const __half2 z = __floats2half2_rn(0.f, 0.f);
  __half2 ac[4][4];
#pragma unroll
  for (int c = 0; c < 4; ++c)
#pragma unroll
    for (int k = 0; k < 4; ++k) ac[c][k] = z;

  int mx = deg[0];
#pragma unroll
  for (int c = 1; c < 4; ++c) if (deg[c] > mx) mx = deg[c];

#pragma unroll 2
  for (int j = 0; j < mx; j += 4) {            // wave-uniform trip count
    int jj = j + sub;
#pragma unroll
    for (int c = 0; c < 4; ++c) {
      int s = __shfl(eid[c], jj < deg[c] ? jj : 0, 64);
      if (jj < deg[c]) {
        union { uint4 u; __half2 h[4]; } v;
        v.u = *(const uint4*)(hin + (size_t)s * H + li * 8);
        ac[c][0] = __hadd2(ac[c][0], v.h[0]);
        ac[c][1] = __hadd2(ac[c][1], v.h[1]);
        ac[c][2] = __hadd2(ac[c][2], v.h[2]);
        ac[c][3] = __hadd2(ac[c][3], v.h[3]);
      }
    }
  }

#pragma unroll
  for (int c = 0; c < 4; ++c) {
    int row = wave * 4 + c;
#pragma unroll
    for (int k = 0; k < 4; ++k) {
      union { __half2 h; unsigned int u; } a, b, d;
      a.h = ac[c][k];
      b.u = __shfl_xor(a.u, 16, 64);
      a.h = __hadd2(a.h, b.h);
      d.u = __shfl_xor(a.u, 32, 64);
      ac[c][k] = __hadd2(a.h, d.h);
    }
    if (sub == 0) {
      float inv = (deg[c] > 0) ? 1.0f / (float)deg[c] : 0.f;
      uint4 o;
      unsigned int* op = (unsigned int*)&o;
#pragma unroll
      for (int k = 0; k < 4; ++k) {
        float lo = __low2float(ac[c][k]) * inv;
        float hi = __high2float(ac[c][k]) * inv;
        op[k] = (unsigned int)f2h(lo) | ((unsigned int)f2h(hi) << 16);
      }
      *(uint4*)&sM[smoff(row, li)] = o;
    }
  }
  __syncthreads();

  // ---- MFMA: wave w -> out-cols [w*16, w*16+16) of the block's 32 nodes ----
  int quad = sub, n16 = li;
  int f0 = wave * 16 + quad * 4;
  float4 bv = *(const float4*)(bg + f0);
#pragma unroll
  for (int t = 0; t < 2; ++t) {
    union { uint4 u; f16x8 h; } bm[4];
#pragma unroll
    for (int ks = 0; ks < 4; ++ks)
      bm[ks].u = *(const uint4*)&sM[smoff(t * 16 + n16, ks * 4 + quad)];

    f32x4 acc = {};
#pragma unroll
    for (int ks = 0; ks < 4; ++ks) {
      union { uint4 u; f16x8 h; } aw;
      aw.u = sW4[(wave * 4 + ks) * 64 + lane];
      acc = __builtin_amdgcn_mfma_f32_16x16x32_f16(aw.h, bm[ks].h, acc, 0, 0, 0);
    }

    int node = nbase + t * 16 + n16;
    ushort4 old = *(const ushort4*)(hin + (size_t)node * H + f0);
    float v0 = h2f(old.x) + acc[0] + bv.x; v0 = v0 > 0.f ? v0 : 0.f;
    float v1 = h2f(old.y) + acc[1] + bv.y; v1 = v1 > 0.f ? v1 : 0.f;
    float v2 = h2f(old.z) + acc[2] + bv.z; v2 = v2 > 0.f ? v2 : 0.f;
    float v3 = h2f(old.w) + acc[3] + bv.w; v3 = v3 > 0.f ? v3 : 0.f;
    *(ushort4*)(hout + (size_t)node * H + f0) = make_ushort4(f2h(v0), f2h(v1),
                                                             f2h(v2), f2h(v3));
  }
}

// ---------------- pool stage 1: per-block partial sums (NO atomics) ---------

__global__ __launch_bounds__(256) void pool_part_k(
    const unsigned short* __restrict__ hb, float* __restrict__ partial, int n) {
  int c  = threadIdx.x & 31;
  int rg = threadIdx.x >> 5;
  float4 acc = {0.f, 0.f, 0.f, 0.f};
#pragma unroll 4
  for (int row = blockIdx.x * 8 + rg; row < n; row += gridDim.x * 8) {
    ushort4 v = ((const ushort4*)(hb + (size_t)row * H))[c];
    acc.x += h2f(v.x); acc.y += h2f(v.y);
    acc.z += h2f(v.z); acc.w += h2f(v.w);
  }
  __shared__ float4 s[256];
  s[threadIdx.x] = acc;
  __syncthreads();
  if (threadIdx.x < 32) {
    float4 t = s[c];
#pragma unroll
    for (int k = 1; k < 8; ++k) {
      float4 q = s[k * 32 + c];
      t.x += q.x; t.y += q.y; t.z += q.z; t.w += q.w;
    }
    *(float4*)&partial[(size_t)blockIdx.x * H + c * 4] = t;
  }
}

// ---------------- pool stage 2: reduce partials + MLP head (1 block) --------

__global__ __launch_bounds__(256) void mlp_k(
    const float* __restrict__ partial,
    const float* __restrict__ W1, const float* __restrict__ b1,
    const float* __restrict__ W2, const float* __restrict__ b2,
    float* __restrict__ out, float invN) {
  __shared__ float g[H];
  __shared__ float hid[H];
  __shared__ float hpart[256];
  __shared__ float gpart[256];
  int tid = threadIdx.x;

  {
    int e = tid & 127, half = tid >> 7;
    const float* pp = partial + (size_t)(half * (POOLB / 2)) * H + e;
    float p0 = 0.f, p1 = 0.f, p2 = 0.f, p3 = 0.f;
#pragma unroll 4
    for (int b = 0; b < POOLB / 2; b += 4) {
      p0 += pp[(size_t)(b + 0) * H];
      p1 += pp[(size_t)(b + 1) * H];
      p2 += pp[(size_t)(b + 2) * H];
      p3 += pp[(size_t)(b + 3) * H];
    }
    gpart[tid] = (p0 + p1) + (p2 + p3);
  }
  __syncthreads();
  if (tid < H) g[tid] = (gpart[tid] + gpart[tid + 128]) * invN;
  __syncthreads();

  {
    int o = tid & 127, half = tid >> 7;
    int k0 = half * 64;
    float p0 = 0.f, p1 = 0.f, p2 = 0.f, p3 = 0.f;
#pragma unroll
    for (int k = 0; k < 64; k += 4) {
      p0 += g[k0 + k + 0] * W1[(k0 + k + 0) * H + o];
      p1 += g[k0 + k + 1] * W1[(k0 + k + 1) * H + o];
      p2 += g[k0 + k + 2] * W1[(k0 + k + 2) * H + o];
      p3 += g[k0 + k + 3] * W1[(k0 + k + 3) * H + o];
    }
    hpart[tid] = (p0 + p1) + (p2 + p3);
  }
  __syncthreads();
  if (tid < H) {
    float v = hpart[tid] + hpart[tid + 128] + b1[tid];
    hid[tid] = v > 0.f ? v : 0.f;
  }
  __syncthreads();
  {
    float q0 = 0.f, q1 = 0.f, q2 = 0.f, q3 = 0.f;
#pragma unroll
    for (int k = 0; k < H; k += 4) {
      q0 += hid[k + 0] * W2[(k + 0) * 256 + tid];
      q1 += hid[k + 1] * W2[(k + 1) * 256 + tid];
      q2 += hid[k + 2] * W2[(k + 2) * 256 + tid];
      q3 += hid[k + 3] * W2[(k + 3) * 256 + tid];
    }
    out[tid] = b2[tid] + (q0 + q1) + (q2 + q3);
  }
}

// ---------------- launcher ----------------

extern "C" void kernel_launch(void* const* d_in, const int* in_sizes, int n_in,
                              void* d_out, int out_size, void* d_ws, size_t ws_size,
                              hipStream_t stream) {
  const float* x  = (const float*)d_in[0];
  const int*   src = (const int*)d_in[1];
  const int*   dst = (const int*)d_in[2];
  const float* Wp = (const float*)d_in[3];
  const float* bp = (const float*)d_in[4];
  const float* Wg = (const float*)d_in[5];
  const float* bg = (const float*)d_in[6];
  const float* W1 = (const float*)d_in[7];
  const float* b1 = (const float*)d_in[8];
  const float* W2 = (const float*)d_in[9];
  const float* b2 = (const float*)d_in[10];
  float* out = (float*)d_out;

  const int N = in_sizes[0] / ND;   // 50000 (< 65536 — ssrc is ushort)
  const int E = in_sizes[1];        // 800000
  const int N_pad = ((N + TILE_R - 1) / TILE_R) * TILE_R;   // 50048 (div by 64)
  const size_t NH = (size_t)N_pad * H;
  const int psz = (N_pad + 7) / 8;                          // 6256 nodes/partition

  char* p = (char*)d_ws;
  unsigned short* hb0   = (unsigned short*)p; p += NH * sizeof(unsigned short);
  unsigned short* hb1   = (unsigned short*)p; p += NH * sizeof(unsigned short);
  unsigned short* wfrag = (unsigned short*)p; p += 3 * 2048 * 8 * sizeof(unsigned short);
  unsigned short* wpfrag= (unsigned short*)p; p += 1024 * 8 * sizeof(unsigned short);
  unsigned short* ssrc  = (unsigned short*)p; p += (size_t)N_pad * CAP * sizeof(unsigned short);
  int*   cnt  = (int*)p;   p += (size_t)N_pad * CSTRIDE * sizeof(int);  // 64B/node
  float* partial = (float*)p; p += (size_t)POOLB * H * sizeof(float);

  const int ntiles = N_pad / TILE_R;

  // D1: weight prep + zero cnt
  prep_all_k<<<20, 256, 0, stream>>>(Wg, Wp, wfrag, wpfrag, cnt, N_pad);

  // D2: scatter || proj (independent; overlapped in one dispatch)
  scatter_proj_k<<<NSCAT + ntiles, 256, 0, stream>>>(src, dst, cnt, ssrc, E, psz,
                                                     x, wpfrag, bp, hb0, N);

  // D3-D5: 3 fused GNN layers (32 nodes/block, 4 chains/wave)
  unsigned short* hin = hb0;
  unsigned short* hout = hb1;
  for (int l = 0; l < 3; ++l) {
    layer_fused512_k<<<N_pad / 32, 512, 0, stream>>>(hin, hout, cnt, ssrc,
                                                     wfrag + (size_t)l * 2048 * 8,
                                                     bg + (size_t)l * H);
    unsigned short* t = hin; hin = hout; hout = t;
  }

  // D6: pool partials (no atomics)   D7: reduce + MLP head
  pool_part_k<<<POOLB, 256, 0, stream>>>(hin, partial, N);
  mlp_k<<<1, 256, 0, stream>>>(partial, W1, b1, W2, b2, out, 1.0f / (float)N);
}